// Round 4
// baseline (317.815 us; speedup 1.0000x reference)
//
#include <hip/hip_runtime.h>
#include <hip/hip_bf16.h>

#define N_SEQ 4096
#define DIM   128
#define NH    4
#define DH    32
#define BATCH 4

// scale = (1/sqrt(32)) * log2(e): softmax computed in exp2 domain
#define QSCALE 0.25503495870989204f

typedef __bf16 bf16x8 __attribute__((ext_vector_type(8)));
typedef __bf16 bf16x2 __attribute__((ext_vector_type(2)));
typedef __bf16 bf16x4 __attribute__((ext_vector_type(4)));
typedef float  f32x4  __attribute__((ext_vector_type(4)));

#define MFMA(a, b, c) __builtin_amdgcn_mfma_f32_16x16x32_bf16((a), (b), (c), 0, 0, 0)

static __device__ __forceinline__ bf16x8 cvt8(const float* __restrict__ p) {
    const float4* f4 = reinterpret_cast<const float4*>(p);
    float4 a = f4[0], b = f4[1];
    bf16x8 r;
    r[0] = (__bf16)a.x; r[1] = (__bf16)a.y; r[2] = (__bf16)a.z; r[3] = (__bf16)a.w;
    r[4] = (__bf16)b.x; r[5] = (__bf16)b.y; r[6] = (__bf16)b.z; r[7] = (__bf16)b.w;
    return r;
}

static __device__ __forceinline__ f32x4 exp4(f32x4 s) {
    f32x4 r;
    r[0] = __builtin_amdgcn_exp2f(s[0]);
    r[1] = __builtin_amdgcn_exp2f(s[1]);
    r[2] = __builtin_amdgcn_exp2f(s[2]);
    r[3] = __builtin_amdgcn_exp2f(s[3]);
    return r;
}

// adjacent-pair writes -> compiler can fuse into packed bf16 converts
static __device__ __forceinline__ bf16x8 pack8(f32x4 a, f32x4 b) {
    bf16x8 o;
    o[0] = (__bf16)a[0]; o[1] = (__bf16)a[1];
    o[2] = (__bf16)a[2]; o[3] = (__bf16)a[3];
    o[4] = (__bf16)b[0]; o[5] = (__bf16)b[1];
    o[6] = (__bf16)b[2]; o[7] = (__bf16)b[3];
    return o;
}

// ---------------------------------------------------------------------------
// Kernel 1: fused QKV projection, operand-SWAPPED MFMA (A=W rows, B=x rows).
// (unchanged — held control)
// ---------------------------------------------------------------------------
__global__ __launch_bounds__(256) void proj_qkv(
    const float* __restrict__ xq, const float* __restrict__ xk, const float* __restrict__ xv,
    const float* __restrict__ Wq, const float* __restrict__ Wk, const float* __restrict__ Wv,
    const float* __restrict__ bq, const float* __restrict__ bk, const float* __restrict__ bv,
    __bf16* __restrict__ Qs, __bf16* __restrict__ Kb, __bf16* __restrict__ Vt)
{
    __shared__ __align__(16) char wlds[34816];        // 128 rows x 272 B
    const int z = blockIdx.z;
    const float* x    = (z == 0) ? xq : ((z == 1) ? xk : xv);
    const float* Wf   = (z == 0) ? Wq : ((z == 1) ? Wk : Wv);
    const float* bias = (z == 0) ? bq : ((z == 1) ? bk : bv);
    const int b    = blockIdx.y;
    const int tid  = threadIdx.x;
    const int wave = tid >> 6, lane = tid & 63;
    const int quad = lane >> 4, l15 = lane & 15;
    const int n0   = blockIdx.x * 64 + wave * 16;

    {   // stage W (fp32 -> bf16) into LDS: thread = half-row
        const int r = tid >> 1, half = tid & 1;
        const float* wsrc = Wf + r * DIM + half * 64;
        char* wdst = wlds + r * 272 + half * 128;
        #pragma unroll
        for (int i = 0; i < 8; i++)
            *(bf16x8*)(wdst + i * 16) = cvt8(wsrc + i * 8);
    }

    bf16x8 a[4];
    const float* xrow = x + (b * N_SEQ + n0 + l15) * DIM + quad * 8;
    a[0] = cvt8(xrow);      a[1] = cvt8(xrow + 32);
    a[2] = cvt8(xrow + 64); a[3] = cvt8(xrow + 96);
    __syncthreads();

    const int n = n0 + l15;                    // D col = n (swapped)
    for (int t = 0; t < 8; t++) {
        const char* wr = wlds + (t * 16 + l15) * 272 + quad * 16;
        bf16x8 w0 = *(const bf16x8*)(wr);
        bf16x8 w1 = *(const bf16x8*)(wr + 64);
        bf16x8 w2 = *(const bf16x8*)(wr + 128);
        bf16x8 w3 = *(const bf16x8*)(wr + 192);

        f32x4 acc = {0.f, 0.f, 0.f, 0.f};
        acc = MFMA(w0, a[0], acc);
        acc = MFMA(w1, a[1], acc);
        acc = MFMA(w2, a[2], acc);
        acc = MFMA(w3, a[3], acc);

        const int d0 = t * 16 + quad * 4;      // D row = d0 + r
        if (z == 0) {
            const int h = d0 >> 5, dh0 = d0 & 31;
            bf16x4 q4;
            #pragma unroll
            for (int r = 0; r < 4; r++)
                q4[r] = (__bf16)((acc[r] + bias[d0 + r]) * QSCALE);
            *(bf16x4*)(Qs + ((b * NH + h) * N_SEQ + n) * DH + dh0) = q4;
        } else if (z == 1) {
            const int h = d0 >> 5, dh0 = d0 & 31;
            bf16x4 k4;
            #pragma unroll
            for (int r = 0; r < 4; r++)
                k4[r] = (__bf16)(acc[r] + bias[d0 + r]);
            *(bf16x4*)(Kb + ((b * NH + h) * N_SEQ + n) * DH + dh0) = k4;
        } else {
            const int nl = n & 63;
            const int np = (n & ~63) | (nl & 35) | ((nl & 12) << 1) | ((nl & 16) >> 2);
            #pragma unroll
            for (int r = 0; r < 4; r++) {
                const int d = d0 + r, h = d >> 5, dh = d & 31;
                Vt[((b * NH + h) * DH + dh) * N_SEQ + np] = (__bf16)(acc[r] + bias[d]);
            }
        }
    }
}

// ---------------------------------------------------------------------------
// Kernel 2: attention — R3's no-LDS direct-from-L2 structure + 4-WAY SPLIT-K.
// R3 post-mortem: removing LDS swapped ~40cy ds_read latency for ~200cy
// L2-hit latency; at 2 waves/SIMD there is no TLP to cover it (both busy%
// fell, duration rose). Fix: keep 64 q/wave and the identical per-key
// instruction stream, but split keys 4 ways (kh = wave, 1024 keys each):
// wave count 2048 -> 4096 = 4 waves/SIMD (kernel is ~108 VGPR <= 128;
// __launch_bounds__(256,4) pins it). Per-wave loop halves; aggregate
// global fragment traffic unchanged (512 MB); grid 1024 keeps bh=bid&15
// so each XCD sees only 2 heads (1 MB, L2-resident). Combine is now a
// 4-way LDS tree (3 partials, 27.6 KB, one barrier).
// Kept from R2/R3: l-sum via ones-MFMA, setprio clusters, named-reg
// double-buffered tile prefetch, zero barriers in the main loop.
// ---------------------------------------------------------------------------
__global__ __launch_bounds__(256, 4) void flash_attn(
    const __bf16* __restrict__ Qs, const __bf16* __restrict__ Kb,
    const __bf16* __restrict__ Vt, __bf16* __restrict__ ctxb)
{
    __shared__ __align__(16) char smem[27648];   // 3 partials x 64 rows x 144 B

    const int bid  = blockIdx.x;
    const int bh   = bid & 15;                 // consecutive blocks cycle heads
    const int qc   = bid >> 4;                 // 0..63, 64 queries each
    const int tid  = threadIdx.x;
    const int wave = tid >> 6, lane = tid & 63;
    const int quad = lane >> 4, l15 = lane & 15;
    const int kh   = wave;                     // 4-way split-K
    const int n0   = qc * 64;
    const int KH   = 1024;                     // keys per kh

    // Q B-fragments: 4 tiles of 16 queries (same 64 queries for all 4 waves)
    const __bf16* Qp = Qs + (bh * N_SEQ + n0) * DH;
    bf16x8 qf[4];
    #pragma unroll
    for (int q = 0; q < 4; q++)
        qf[q] = *(const bf16x8*)(Qp + (q * 16 + l15) * DH + quad * 8);

    // ones A-fragment for the l-sum MFMA (l = 1*P summed over frag keys)
    bf16x8 ones;
    #pragma unroll
    for (int i = 0; i < 8; i++) ones[i] = (__bf16)1.0f;

    // per-lane global fragment bases (this wave's 1024-key quarter)
    const __bf16* gK  = Kb + ((size_t)bh * N_SEQ + kh * KH + l15) * DH + quad * 8;
    const __bf16* gV0 = Vt + ((size_t)bh * DH + l15) * N_SEQ + kh * KH + quad * 8;
    const __bf16* gV1 = gV0 + 16 * N_SEQ;

#define LOADT(t, k0,k1,k2,k3, v0,v1,v2,v3) do {                         \
    const int _t = (t) & 15;                                            \
    const __bf16* _k = gK + (size_t)(_t * 64) * DH;                     \
    k0 = *(const bf16x8*)(_k);                                          \
    k1 = *(const bf16x8*)(_k + 16 * DH);                                \
    k2 = *(const bf16x8*)(_k + 32 * DH);                                \
    k3 = *(const bf16x8*)(_k + 48 * DH);                                \
    v0 = *(const bf16x8*)(gV0 + _t * 64);                               \
    v1 = *(const bf16x8*)(gV1 + _t * 64);                               \
    v2 = *(const bf16x8*)(gV0 + _t * 64 + 32);                          \
    v3 = *(const bf16x8*)(gV1 + _t * 64 + 32);                          \
} while (0)

#define COMPUTE(k0,k1,k2,k3, v0,v1,v2,v3) do {                          \
    bf16x8 pf[4][2];                                                    \
    _Pragma("unroll")                                                   \
    for (int q = 0; q < 4; q++) {                                       \
        __builtin_amdgcn_s_setprio(1);                                  \
        f32x4 sa = MFMA(k0, qf[q], z4);                                 \
        f32x4 sb = MFMA(k1, qf[q], z4);                                 \
        f32x4 sc = MFMA(k2, qf[q], z4);                                 \
        f32x4 sd = MFMA(k3, qf[q], z4);                                 \
        __builtin_amdgcn_s_setprio(0);                                  \
        f32x4 ea = exp4(sa), eb = exp4(sb), ec = exp4(sc), ed = exp4(sd); \
        pf[q][0] = pack8(ea, eb);                                       \
        pf[q][1] = pack8(ec, ed);                                       \
    }                                                                   \
    __builtin_amdgcn_s_setprio(1);                                      \
    _Pragma("unroll")                                                   \
    for (int q = 0; q < 4; q++) {                                       \
        c[q][0] = MFMA(v0, pf[q][0], c[q][0]);                          \
        c[q][1] = MFMA(v1, pf[q][0], c[q][1]);                          \
        c[q][0] = MFMA(v2, pf[q][1], c[q][0]);                          \
        c[q][1] = MFMA(v3, pf[q][1], c[q][1]);                          \
        cl[q]   = MFMA(ones, pf[q][0], cl[q]);                          \
        cl[q]   = MFMA(ones, pf[q][1], cl[q]);                          \
    }                                                                   \
    __builtin_amdgcn_s_setprio(0);                                      \
} while (0)

    f32x4 c[4][2];
    f32x4 cl[4];
    const f32x4 z4 = {0.f,0.f,0.f,0.f};
    #pragma unroll
    for (int q = 0; q < 4; q++) { c[q][0] = z4; c[q][1] = z4; cl[q] = z4; }

    // double-buffered fragment registers (named — rule #20)
    bf16x8 kA0,kA1,kA2,kA3, vA0,vA1,vA2,vA3;
    bf16x8 kB0,kB1,kB2,kB3, vB0,vB1,vB2,vB3;

    LOADT(0, kA0,kA1,kA2,kA3, vA0,vA1,vA2,vA3);

    for (int t = 0; t < 16; t += 2) {          // 16 tiles of 64 keys, no barriers
        LOADT(t + 1, kB0,kB1,kB2,kB3, vB0,vB1,vB2,vB3);
        COMPUTE(kA0,kA1,kA2,kA3, vA0,vA1,vA2,vA3);
        LOADT(t + 2, kA0,kA1,kA2,kA3, vA0,vA1,vA2,vA3);
        COMPUTE(kB0,kB1,kB2,kB3, vB0,vB1,vB2,vB3);
    }

#undef LOADT
#undef COMPUTE

    // 4-way split-K combine: waves 1..3 store partials, wave 0 reduces.
    if (kh != 0) {
        char* dst = smem + ((kh - 1) * 64 + lane) * 144;
        #pragma unroll
        for (int q = 0; q < 4; q++) {
            *(f32x4*)(dst + (q * 2 + 0) * 16) = c[q][0];
            *(f32x4*)(dst + (q * 2 + 1) * 16) = c[q][1];
        }
        f32x4 lv = {cl[0][0], cl[1][0], cl[2][0], cl[3][0]};
        *(f32x4*)(dst + 128) = lv;
    }
    __syncthreads();
    if (kh == 0) {
        float lsum[4];
        #pragma unroll
        for (int q = 0; q < 4; q++) lsum[q] = cl[q][0];
        #pragma unroll
        for (int w = 0; w < 3; w++) {
            const char* src = smem + (w * 64 + lane) * 144;
            f32x4 lp = *(const f32x4*)(src + 128);
            #pragma unroll
            for (int q = 0; q < 4; q++) {
                c[q][0] += *(const f32x4*)(src + (q * 2 + 0) * 16);
                c[q][1] += *(const f32x4*)(src + (q * 2 + 1) * 16);
                lsum[q] += lp[q];
            }
        }
        const int b = bh >> 2, h = bh & 3;
        #pragma unroll
        for (int q = 0; q < 4; q++) {
            const float inv = 1.0f / lsum[q];
            const int qg = n0 + q * 16 + l15;
            __bf16* dst = ctxb + ((size_t)(b * N_SEQ + qg)) * DIM + h * DH + quad * 4;
            #pragma unroll
            for (int dt = 0; dt < 2; dt++) {
                f32x4 cc = c[q][dt];
                bf16x2 e0 = {(__bf16)(cc[0] * inv), (__bf16)(cc[1] * inv)};
                bf16x2 e1 = {(__bf16)(cc[2] * inv), (__bf16)(cc[3] * inv)};
                *(bf16x2*)(dst + dt * 16)     = e0;
                *(bf16x2*)(dst + dt * 16 + 2) = e1;
            }
        }
    }
}

// ---------------------------------------------------------------------------
// Kernel 3: output projection, operand-swapped + Wo staged in LDS.
// (unchanged — held control)
// ---------------------------------------------------------------------------
__global__ __launch_bounds__(256) void out_proj(
    const __bf16* __restrict__ ctxb, const float* __restrict__ Wo,
    const float* __restrict__ bo, float* __restrict__ out)
{
    __shared__ __align__(16) char wlds[34816];
    const int b    = blockIdx.y;
    const int tid  = threadIdx.x;
    const int wave = tid >> 6, lane = tid & 63;
    const int quad = lane >> 4, l15 = lane & 15;
    const int n0   = blockIdx.x * 64 + wave * 16;

    {   // stage Wo (fp32 -> bf16) into LDS
        const int r = tid >> 1, half = tid & 1;
        const float* wsrc = Wo + r * DIM + half * 64;
        char* wdst = wlds + r * 272 + half * 128;
        #pragma unroll
        for (int i = 0; i < 8; i++)
            *(bf16x8*)(wdst + i * 16) = cvt8(wsrc + i * 8);
    }

    bf16x8 a[4];
    const __bf16* crow = ctxb + (b * N_SEQ + n0 + l15) * DIM + quad * 8;
    a[0] = *(const bf16x8*)(crow);
    a[1] = *(const bf16x8*)(crow + 32);
    a[2] = *(const bf16x8*)(crow + 64);
    a[3] = *(const bf16x8*)(crow + 96);
    __syncthreads();

    const int n = n0 + l15;
    for (int t = 0; t < 8; t++) {
        const char* wr = wlds + (t * 16 + l15) * 272 + quad * 16;
        bf16x8 w0 = *(const bf16x8*)(wr);
        bf16x8 w1 = *(const bf16x8*)(wr + 64);
        bf16x8 w2 = *(const bf16x8*)(wr + 128);
        bf16x8 w3 = *(const bf16x8*)(wr + 192);

        f32x4 acc = {0.f, 0.f, 0.f, 0.f};
        acc = MFMA(w0, a[0], acc);
        acc = MFMA(w1, a[1], acc);
        acc = MFMA(w2, a[2], acc);
        acc = MFMA(w3, a[3], acc);

        const int d0 = t * 16 + quad * 4;
        float4 o;
        o.x = acc[0] + bo[d0];
        o.y = acc[1] + bo[d0 + 1];
        o.z = acc[2] + bo[d0 + 2];
        o.w = acc[3] + bo[d0 + 3];
        *(float4*)(out + (b * N_SEQ + n) * DIM + d0) = o;
    }
}

// ---------------------------------------------------------------------------
extern "C" void kernel_launch(void* const* d_in, const int* in_sizes, int n_in,
                              void* d_out, int out_size, void* d_ws, size_t ws_size,
                              hipStream_t stream)
{
    const float* query = (const float*)d_in[0];
    const float* key   = (const float*)d_in[1];
    const float* value = (const float*)d_in[2];
    const float* Wq = (const float*)d_in[3];
    const float* bq = (const float*)d_in[4];
    const float* Wk = (const float*)d_in[5];
    const float* bk = (const float*)d_in[6];
    const float* Wv = (const float*)d_in[7];
    const float* bv = (const float*)d_in[8];
    const float* Wo = (const float*)d_in[9];
    const float* bo = (const float*)d_in[10];
    float* out = (float*)d_out;

    char* ws = (char*)d_ws;
    const size_t e = (size_t)BATCH * N_SEQ * DIM;   // 2,097,152 elements
    __bf16* Qs   = (__bf16*)(ws);                   // 4 MB  [B,H,N,32] scaled
    __bf16* Kb   = (__bf16*)(ws + 2 * e);           // 4 MB  [B,H,N,32] identity
    __bf16* Vt   = (__bf16*)(ws + 4 * e);           // 4 MB  [B,H,32,N] key-permuted
    __bf16* ctxb = (__bf16*)(ws + 6 * e);           // 4 MB  [B,N,128]

    proj_qkv<<<dim3(64, BATCH, 3), 256, 0, stream>>>(
        query, key, value, Wq, Wk, Wv, bq, bk, bv, Qs, Kb, Vt);
    flash_attn<<<dim3(1024), 256, 0, stream>>>(Qs, Kb, Vt, ctxb);
    out_proj<<<dim3(64, BATCH), 256, 0, stream>>>(ctxb, Wo, bo, out);
}

// Round 5
// 149.738 us; speedup vs baseline: 2.1225x; 2.1225x over previous
//
#include <hip/hip_runtime.h>
#include <hip/hip_bf16.h>

#define N_SEQ 4096
#define DIM   128
#define NH    4
#define DH    32
#define BATCH 4

// scale = (1/sqrt(32)) * log2(e): softmax computed in exp2 domain
#define QSCALE 0.25503495870989204f

typedef __bf16 bf16x8 __attribute__((ext_vector_type(8)));
typedef __bf16 bf16x2 __attribute__((ext_vector_type(2)));
typedef __bf16 bf16x4 __attribute__((ext_vector_type(4)));
typedef float  f32x4  __attribute__((ext_vector_type(4)));

#define MFMA(a, b, c) __builtin_amdgcn_mfma_f32_16x16x32_bf16((a), (b), (c), 0, 0, 0)

static __device__ __forceinline__ bf16x8 cvt8(const float* __restrict__ p) {
    const float4* f4 = reinterpret_cast<const float4*>(p);
    float4 a = f4[0], b = f4[1];
    bf16x8 r;
    r[0] = (__bf16)a.x; r[1] = (__bf16)a.y; r[2] = (__bf16)a.z; r[3] = (__bf16)a.w;
    r[4] = (__bf16)b.x; r[5] = (__bf16)b.y; r[6] = (__bf16)b.z; r[7] = (__bf16)b.w;
    return r;
}

static __device__ __forceinline__ f32x4 exp4(f32x4 s) {
    f32x4 r;
    r[0] = __builtin_amdgcn_exp2f(s[0]);
    r[1] = __builtin_amdgcn_exp2f(s[1]);
    r[2] = __builtin_amdgcn_exp2f(s[2]);
    r[3] = __builtin_amdgcn_exp2f(s[3]);
    return r;
}

// adjacent-pair writes -> compiler can fuse into packed bf16 converts
static __device__ __forceinline__ bf16x8 pack8(f32x4 a, f32x4 b) {
    bf16x8 o;
    o[0] = (__bf16)a[0]; o[1] = (__bf16)a[1];
    o[2] = (__bf16)a[2]; o[3] = (__bf16)a[3];
    o[4] = (__bf16)b[0]; o[5] = (__bf16)b[1];
    o[6] = (__bf16)b[2]; o[7] = (__bf16)b[3];
    return o;
}

// ---------------------------------------------------------------------------
// Kernel 1: fused QKV projection, operand-SWAPPED MFMA (A=W rows, B=x rows).
// (unchanged — held control)
// ---------------------------------------------------------------------------
__global__ __launch_bounds__(256) void proj_qkv(
    const float* __restrict__ xq, const float* __restrict__ xk, const float* __restrict__ xv,
    const float* __restrict__ Wq, const float* __restrict__ Wk, const float* __restrict__ Wv,
    const float* __restrict__ bq, const float* __restrict__ bk, const float* __restrict__ bv,
    __bf16* __restrict__ Qs, __bf16* __restrict__ Kb, __bf16* __restrict__ Vt)
{
    __shared__ __align__(16) char wlds[34816];        // 128 rows x 272 B
    const int z = blockIdx.z;
    const float* x    = (z == 0) ? xq : ((z == 1) ? xk : xv);
    const float* Wf   = (z == 0) ? Wq : ((z == 1) ? Wk : Wv);
    const float* bias = (z == 0) ? bq : ((z == 1) ? bk : bv);
    const int b    = blockIdx.y;
    const int tid  = threadIdx.x;
    const int wave = tid >> 6, lane = tid & 63;
    const int quad = lane >> 4, l15 = lane & 15;
    const int n0   = blockIdx.x * 64 + wave * 16;

    {   // stage W (fp32 -> bf16) into LDS: thread = half-row
        const int r = tid >> 1, half = tid & 1;
        const float* wsrc = Wf + r * DIM + half * 64;
        char* wdst = wlds + r * 272 + half * 128;
        #pragma unroll
        for (int i = 0; i < 8; i++)
            *(bf16x8*)(wdst + i * 16) = cvt8(wsrc + i * 8);
    }

    bf16x8 a[4];
    const float* xrow = x + (b * N_SEQ + n0 + l15) * DIM + quad * 8;
    a[0] = cvt8(xrow);      a[1] = cvt8(xrow + 32);
    a[2] = cvt8(xrow + 64); a[3] = cvt8(xrow + 96);
    __syncthreads();

    const int n = n0 + l15;                    // D col = n (swapped)
    for (int t = 0; t < 8; t++) {
        const char* wr = wlds + (t * 16 + l15) * 272 + quad * 16;
        bf16x8 w0 = *(const bf16x8*)(wr);
        bf16x8 w1 = *(const bf16x8*)(wr + 64);
        bf16x8 w2 = *(const bf16x8*)(wr + 128);
        bf16x8 w3 = *(const bf16x8*)(wr + 192);

        f32x4 acc = {0.f, 0.f, 0.f, 0.f};
        acc = MFMA(w0, a[0], acc);
        acc = MFMA(w1, a[1], acc);
        acc = MFMA(w2, a[2], acc);
        acc = MFMA(w3, a[3], acc);

        const int d0 = t * 16 + quad * 4;      // D row = d0 + r
        if (z == 0) {
            const int h = d0 >> 5, dh0 = d0 & 31;
            bf16x4 q4;
            #pragma unroll
            for (int r = 0; r < 4; r++)
                q4[r] = (__bf16)((acc[r] + bias[d0 + r]) * QSCALE);
            *(bf16x4*)(Qs + ((b * NH + h) * N_SEQ + n) * DH + dh0) = q4;
        } else if (z == 1) {
            const int h = d0 >> 5, dh0 = d0 & 31;
            bf16x4 k4;
            #pragma unroll
            for (int r = 0; r < 4; r++)
                k4[r] = (__bf16)(acc[r] + bias[d0 + r]);
            *(bf16x4*)(Kb + ((b * NH + h) * N_SEQ + n) * DH + dh0) = k4;
        } else {
            const int nl = n & 63;
            const int np = (n & ~63) | (nl & 35) | ((nl & 12) << 1) | ((nl & 16) >> 2);
            #pragma unroll
            for (int r = 0; r < 4; r++) {
                const int d = d0 + r, h = d >> 5, dh = d & 31;
                Vt[((b * NH + h) * DH + dh) * N_SEQ + np] = (__bf16)(acc[r] + bias[d]);
            }
        }
    }
}

// ---------------------------------------------------------------------------
// Kernel 2: attention — CLEAN 4-waves/SIMD TEST (rounds 1/4 both spilled:
// VGPR_Count=64 + WRITE_SIZE 17MB/650MB proved launch_bounds capped the
// unified reg file below the structure's live set; the TLP idea was never
// actually tested). This version shrinks BOTH the register state AND the
// LDS footprint so 16 waves/CU fit without spilling:
//   - 32 q/wave, 2-way split-K, 4 waves/block, 1024 blocks = 4 blocks/CU
//   - single-64-key-tile double buffer: LDS 38912 B (4 blocks/CU capacity)
//   - per-wave regs: qf 8 + c 16 + cl 8 + kf/vf 32 + prefetch 16 ~ <=128
// Cross-BLOCK overlap (independent barrier domains, m114) covers the
// per-tile barrier + chain stalls that lockstep waves cannot.
// Kept verified wins: l-sum via ones-MFMA, setprio clusters, pack8, LDS
// staging (R3 showed L2-direct is worse at low TLP; LDS read latency is
// 5x lower). Spill tripwire: WRITE_SIZE must stay ~4 MB.
// ---------------------------------------------------------------------------
__global__ __launch_bounds__(256, 4) void flash_attn(
    const __bf16* __restrict__ Qs, const __bf16* __restrict__ Kb,
    const __bf16* __restrict__ Vt, __bf16* __restrict__ ctxb)
{
    // K: 2 kh x 2 buf x 5120 = 20480 ; V: 2 kh x 2 buf x 4608 = 18432
    __shared__ __align__(16) char smem[38912];
    char* const Kbase = smem;                  // + kh*10240 + cur*5120
    char* const Vbase = smem + 20480;          // + kh*9216  + cur*4608

    const int bid  = blockIdx.x;
    const int bh   = bid & 15;                 // consecutive blocks cycle heads
    const int qc   = bid >> 4;                 // 0..63, 64 queries each
    const int tid  = threadIdx.x;
    const int wave = tid >> 6, lane = tid & 63;
    const int quad = lane >> 4, l15 = lane & 15;
    const int qh   = wave & 1, kh = wave >> 1; // kh in {0,1}
    const int n0   = qc * 64 + qh * 32;
    const int KH   = 2048;                     // keys per kh

    // Q B-fragments: 2 tiles of 16 queries
    const __bf16* Qp = Qs + (bh * N_SEQ + n0) * DH;
    bf16x8 qf[2];
    qf[0] = *(const bf16x8*)(Qp + l15 * DH + quad * 8);
    qf[1] = *(const bf16x8*)(Qp + (16 + l15) * DH + quad * 8);

    // ones A-fragment for the l-sum MFMA (l = 1*P summed over frag keys)
    bf16x8 ones;
    #pragma unroll
    for (int i = 0; i < 8; i++) ones[i] = (__bf16)1.0f;

    // staging: thread covers one 16B chunk of the K tile and one of the V
    // tile, for BOTH kh groups (2 K + 2 V loads / 64-key step)
    const int r_ = tid >> 2, c_ = tid & 3;
    const __bf16* gK = Kb + (size_t)bh * N_SEQ * DH + r_ * DH + c_ * 8;
    const __bf16* gV = Vt + ((size_t)bh * DH + (tid >> 3)) * N_SEQ + (tid & 7) * 8;
    const int kofsK = r_ * 80 + c_ * 16;
    const int kofsV = (tid >> 3) * 144 + (tid & 7) * 16;

    {   // prologue: tile 0 of both kh groups -> buf 0
        #pragma unroll
        for (int g = 0; g < 2; g++) {
            bf16x8 kr = *(const bf16x8*)(gK + (size_t)(g * KH) * DH);
            bf16x8 vr = *(const bf16x8*)(gV + g * KH);
            *(bf16x8*)(Kbase + g * 10240 + kofsK) = kr;
            *(bf16x8*)(Vbase + g * 9216  + kofsV) = vr;
        }
    }
    __syncthreads();

    char* const Kme = Kbase + kh * 10240;
    char* const Vme = Vbase + kh * 9216;

    f32x4 c[2][2];
    f32x4 cl[2];
    const f32x4 z4 = {0.f,0.f,0.f,0.f};
    c[0][0] = z4; c[0][1] = z4; c[1][0] = z4; c[1][1] = z4;
    cl[0] = z4; cl[1] = z4;

    for (int t = 0; t < 32; t++) {             // 32 tiles of 64 keys
        const int cur = t & 1;
        const char* Kt  = Kme + cur * 5120;
        const char* Vtl = Vme + cur * 4608;

        // prefetch next tile for both kh groups (wraps; harmless)
        const int kn = (t + 1) & 31;
        bf16x8 kr0 = *(const bf16x8*)(gK + (size_t)(kn * 64) * DH);
        bf16x8 kr1 = *(const bf16x8*)(gK + (size_t)(KH + kn * 64) * DH);
        bf16x8 vr0 = *(const bf16x8*)(gV + kn * 64);
        bf16x8 vr1 = *(const bf16x8*)(gV + KH + kn * 64);

        // K A-frags (identity layout; rows 16i+l15)
        bf16x8 kf0 = *(const bf16x8*)(Kt + l15 * 80 + quad * 16);
        bf16x8 kf1 = *(const bf16x8*)(Kt + (16 + l15) * 80 + quad * 16);
        bf16x8 kf2 = *(const bf16x8*)(Kt + (32 + l15) * 80 + quad * 16);
        bf16x8 kf3 = *(const bf16x8*)(Kt + (48 + l15) * 80 + quad * 16);

        // scores + P (in registers) per query tile
        bf16x8 pf[2][2];
        #pragma unroll
        for (int q = 0; q < 2; q++) {
            __builtin_amdgcn_s_setprio(1);
            f32x4 sa = MFMA(kf0, qf[q], z4);
            f32x4 sb = MFMA(kf1, qf[q], z4);
            f32x4 sc = MFMA(kf2, qf[q], z4);
            f32x4 sd = MFMA(kf3, qf[q], z4);
            __builtin_amdgcn_s_setprio(0);
            f32x4 ea = exp4(sa), eb = exp4(sb), ec = exp4(sc), ed = exp4(sd);
            pf[q][0] = pack8(ea, eb);          // keys g0
            pf[q][1] = pack8(ec, ed);          // keys g1
        }

        // V^T A-frags (stride 144, key-group via +64)
        bf16x8 vf0 = *(const bf16x8*)(Vtl + l15 * 144 + quad * 16);
        bf16x8 vf1 = *(const bf16x8*)(Vtl + (16 + l15) * 144 + quad * 16);
        bf16x8 vf2 = *(const bf16x8*)(Vtl + l15 * 144 + 64 + quad * 16);
        bf16x8 vf3 = *(const bf16x8*)(Vtl + (16 + l15) * 144 + 64 + quad * 16);

        __builtin_amdgcn_s_setprio(1);
        #pragma unroll
        for (int q = 0; q < 2; q++) {
            c[q][0] = MFMA(vf0, pf[q][0], c[q][0]);
            c[q][1] = MFMA(vf1, pf[q][0], c[q][1]);
            c[q][0] = MFMA(vf2, pf[q][1], c[q][0]);
            c[q][1] = MFMA(vf3, pf[q][1], c[q][1]);
            cl[q]   = MFMA(ones, pf[q][0], cl[q]);   // l-sum on MFMA pipe
            cl[q]   = MFMA(ones, pf[q][1], cl[q]);
        }
        __builtin_amdgcn_s_setprio(0);

        // stage next tile into the other buffer
        *(bf16x8*)(Kbase + (cur ^ 1) * 5120 + kofsK)          = kr0;
        *(bf16x8*)(Kbase + 10240 + (cur ^ 1) * 5120 + kofsK)  = kr1;
        *(bf16x8*)(Vbase + (cur ^ 1) * 4608 + kofsV)          = vr0;
        *(bf16x8*)(Vbase + 9216 + (cur ^ 1) * 4608 + kofsV)   = vr1;
        __syncthreads();
    }

    // split-K combine via the dead K LDS region (128 rows x 80 B = 10240 B)
    if (kh == 1) {
        char* dst = smem + (qh * 64 + lane) * 80;
        #pragma unroll
        for (int q = 0; q < 2; q++) {
            *(f32x4*)(dst + q * 32)      = c[q][0];
            *(f32x4*)(dst + q * 32 + 16) = c[q][1];
        }
        float2 lv = {cl[0][0], cl[1][0]};
        *(float2*)(dst + 64) = lv;
    }
    __syncthreads();
    if (kh == 0) {
        const char* src = smem + (qh * 64 + lane) * 80;
        float2 lp = *(const float2*)(src + 64);
        const float lpa[2] = {lp.x, lp.y};
        const int b = bh >> 2, h = bh & 3;
        #pragma unroll
        for (int q = 0; q < 2; q++) {
            c[q][0] += *(const f32x4*)(src + q * 32);
            c[q][1] += *(const f32x4*)(src + q * 32 + 16);
            const float inv = 1.0f / (cl[q][0] + lpa[q]);
            const int qg = n0 + q * 16 + l15;
            __bf16* dst = ctxb + ((size_t)(b * N_SEQ + qg)) * DIM + h * DH + quad * 4;
            #pragma unroll
            for (int dt = 0; dt < 2; dt++) {
                f32x4 cc = c[q][dt];
                bf16x2 e0 = {(__bf16)(cc[0] * inv), (__bf16)(cc[1] * inv)};
                bf16x2 e1 = {(__bf16)(cc[2] * inv), (__bf16)(cc[3] * inv)};
                *(bf16x2*)(dst + dt * 16)     = e0;
                *(bf16x2*)(dst + dt * 16 + 2) = e1;
            }
        }
    }
}

// ---------------------------------------------------------------------------
// Kernel 3: output projection, operand-swapped + Wo staged in LDS.
// (unchanged — held control)
// ---------------------------------------------------------------------------
__global__ __launch_bounds__(256) void out_proj(
    const __bf16* __restrict__ ctxb, const float* __restrict__ Wo,
    const float* __restrict__ bo, float* __restrict__ out)
{
    __shared__ __align__(16) char wlds[34816];
    const int b    = blockIdx.y;
    const int tid  = threadIdx.x;
    const int wave = tid >> 6, lane = tid & 63;
    const int quad = lane >> 4, l15 = lane & 15;
    const int n0   = blockIdx.x * 64 + wave * 16;

    {   // stage Wo (fp32 -> bf16) into LDS
        const int r = tid >> 1, half = tid & 1;
        const float* wsrc = Wo + r * DIM + half * 64;
        char* wdst = wlds + r * 272 + half * 128;
        #pragma unroll
        for (int i = 0; i < 8; i++)
            *(bf16x8*)(wdst + i * 16) = cvt8(wsrc + i * 8);
    }

    bf16x8 a[4];
    const __bf16* crow = ctxb + (b * N_SEQ + n0 + l15) * DIM + quad * 8;
    a[0] = *(const bf16x8*)(crow);
    a[1] = *(const bf16x8*)(crow + 32);
    a[2] = *(const bf16x8*)(crow + 64);
    a[3] = *(const bf16x8*)(crow + 96);
    __syncthreads();

    const int n = n0 + l15;
    for (int t = 0; t < 8; t++) {
        const char* wr = wlds + (t * 16 + l15) * 272 + quad * 16;
        bf16x8 w0 = *(const bf16x8*)(wr);
        bf16x8 w1 = *(const bf16x8*)(wr + 64);
        bf16x8 w2 = *(const bf16x8*)(wr + 128);
        bf16x8 w3 = *(const bf16x8*)(wr + 192);

        f32x4 acc = {0.f, 0.f, 0.f, 0.f};
        acc = MFMA(w0, a[0], acc);
        acc = MFMA(w1, a[1], acc);
        acc = MFMA(w2, a[2], acc);
        acc = MFMA(w3, a[3], acc);

        const int d0 = t * 16 + quad * 4;
        float4 o;
        o.x = acc[0] + bo[d0];
        o.y = acc[1] + bo[d0 + 1];
        o.z = acc[2] + bo[d0 + 2];
        o.w = acc[3] + bo[d0 + 3];
        *(float4*)(out + (b * N_SEQ + n) * DIM + d0) = o;
    }
}

// ---------------------------------------------------------------------------
extern "C" void kernel_launch(void* const* d_in, const int* in_sizes, int n_in,
                              void* d_out, int out_size, void* d_ws, size_t ws_size,
                              hipStream_t stream)
{
    const float* query = (const float*)d_in[0];
    const float* key   = (const float*)d_in[1];
    const float* value = (const float*)d_in[2];
    const float* Wq = (const float*)d_in[3];
    const float* bq = (const float*)d_in[4];
    const float* Wk = (const float*)d_in[5];
    const float* bk = (const float*)d_in[6];
    const float* Wv = (const float*)d_in[7];
    const float* bv = (const float*)d_in[8];
    const float* Wo = (const float*)d_in[9];
    const float* bo = (const float*)d_in[10];
    float* out = (float*)d_out;

    char* ws = (char*)d_ws;
    const size_t e = (size_t)BATCH * N_SEQ * DIM;   // 2,097,152 elements
    __bf16* Qs   = (__bf16*)(ws);                   // 4 MB  [B,H,N,32] scaled
    __bf16* Kb   = (__bf16*)(ws + 2 * e);           // 4 MB  [B,H,N,32] identity
    __bf16* Vt   = (__bf16*)(ws + 4 * e);           // 4 MB  [B,H,32,N] key-permuted
    __bf16* ctxb = (__bf16*)(ws + 6 * e);           // 4 MB  [B,N,128]

    proj_qkv<<<dim3(64, BATCH, 3), 256, 0, stream>>>(
        query, key, value, Wq, Wk, Wv, bq, bk, bv, Qs, Kb, Vt);
    flash_attn<<<dim3(1024), 256, 0, stream>>>(Qs, Kb, Vt, ctxb);
    out_proj<<<dim3(64, BATCH), 256, 0, stream>>>(ctxb, Wo, bo, out);
}